// Round 4
// baseline (358.401 us; speedup 1.0000x reference)
//
#include <hip/hip_runtime.h>
#include <hip/hip_bf16.h>

// FullAttention fwd, B=4 L=S=2048 H=8 E=D=64, fp32 in/out.
// Round 4: same math as R3 (prescaled-Q static-max softmax, S^T=K*Q^T via
// mfma 16x16x32, P-from-registers PV via mfma 16x16x16bf16_1k, cross-wave
// O reduce), but the K-loop is a single-barrier double-buffered DMA pipeline:
//   stage(next buf via global_load_lds) -> compute(cur buf) -> __syncthreads()
// All LDS writes are DMA (no ds_write in the loop), so one barrier per tile is
// sufficient and the vmcnt(0) drain at the barrier lands AFTER compute ->
// global->LDS latency overlaps compute. Buffers are distinct __shared__ arrays
// (loop unrolled x2) so AA can prove the cur-buf ds_reads don't alias the
// in-flight DMA into the other buffer.

#define BNUM 4
#define LLEN 2048
#define SLEN 2048
#define HNUM 8
#define EDIM 64

typedef __attribute__((ext_vector_type(8))) short bf16x8;
typedef __attribute__((ext_vector_type(4))) short bf16x4;
typedef __attribute__((ext_vector_type(4))) float f32x4;

__device__ __forceinline__ short f2bf(float f) {
    union { __hip_bfloat16 b; short s; } u;
    u.b = __float2bfloat16(f);
    return u.s;
}

#if __has_builtin(__builtin_amdgcn_global_load_lds)
#define HAVE_GLL 1
#else
#define HAVE_GLL 0
#endif

__device__ __forceinline__ void stage16(const short* g, short* l) {
#if HAVE_GLL
    __builtin_amdgcn_global_load_lds(
        (const __attribute__((address_space(1))) void*)g,
        (__attribute__((address_space(3))) void*)l, 16, 0, 0);
#else
    *(bf16x8*)l = *(const bf16x8*)g;
#endif
}

// ---- pre-pass (single launch): role = blockIdx.y ----
__global__ __launch_bounds__(256)
void prep(const float* __restrict__ Qg, const float* __restrict__ Kg,
          const float* __restrict__ Vg,
          short* __restrict__ Qc, short* __restrict__ Kc, short* __restrict__ Vt)
{
    __shared__ short tile[EDIM][80];
    const int role = blockIdx.y;
    if (role == 0) {
        const size_t t = (size_t)blockIdx.x * 256 + threadIdx.x;
        const float c = 0.18033688011112042f;   // (1/sqrt(64)) * log2(e)
        const float4* src = (const float4*)Qg + t * 2;
        float4 a = src[0], bb = src[1];
        bf16x8 o;
        o[0]=f2bf(a.x*c);  o[1]=f2bf(a.y*c);  o[2]=f2bf(a.z*c);  o[3]=f2bf(a.w*c);
        o[4]=f2bf(bb.x*c); o[5]=f2bf(bb.y*c); o[6]=f2bf(bb.z*c); o[7]=f2bf(bb.w*c);
        *((bf16x8*)Qc + t) = o;
    } else if (role == 1) {
        const int t = blockIdx.x * 256 + threadIdx.x;
        const int e8 = t & 7;
        const int tmp = t >> 3;
        const int h = tmp & 7;
        const int tmp2 = tmp >> 3;
        const int s = tmp2 & (SLEN - 1);
        const int b = tmp2 >> 11;
        const float4* src = (const float4*)(Kg + (((size_t)(b * SLEN + s) * HNUM + h) * EDIM + e8 * 8));
        float4 a = src[0], bb = src[1];
        bf16x8 o;
        o[0]=f2bf(a.x);  o[1]=f2bf(a.y);  o[2]=f2bf(a.z);  o[3]=f2bf(a.w);
        o[4]=f2bf(bb.x); o[5]=f2bf(bb.y); o[6]=f2bf(bb.z); o[7]=f2bf(bb.w);
        *(bf16x8*)(Kc + ((size_t)((b * HNUM + h) * SLEN + s) * EDIM + e8 * 8)) = o;
    } else {
        if (blockIdx.x >= 1024) return;
        const int x = blockIdx.x;
        const int s0 = (x & 31) * 64;
        const int bh = x >> 5;
        const int b = bh >> 3, h = bh & 7;
        {
            const int sr = threadIdx.x >> 2, dc = (threadIdx.x & 3) * 16;
            const float4* src = (const float4*)(Vg + (((size_t)(b * SLEN + s0 + sr) * HNUM + h) * EDIM + dc));
            #pragma unroll
            for (int j4 = 0; j4 < 4; ++j4) {
                float4 a = src[j4];
                tile[dc + j4*4 + 0][sr] = f2bf(a.x);
                tile[dc + j4*4 + 1][sr] = f2bf(a.y);
                tile[dc + j4*4 + 2][sr] = f2bf(a.z);
                tile[dc + j4*4 + 3][sr] = f2bf(a.w);
            }
        }
        __syncthreads();
        {
            const int dr = threadIdx.x >> 2, sc = (threadIdx.x & 3) * 16;
            short* dst = Vt + ((size_t)((b * HNUM + h) * EDIM + dr) * SLEN + s0 + sc);
            *(bf16x8*)dst       = *(const bf16x8*)&tile[dr][sc];
            *(bf16x8*)(dst + 8) = *(const bf16x8*)&tile[dr][sc + 8];
        }
    }
}

// ---- main kernel ----
// LDS tile layout (K and V^T halves): 64 rows x 8 chunks of 16B; chunk (r,c)
// stored at linear chunk r*8 + (c ^ (r&7)). Staging lane L (inst p) covers
// r = wave*16 + p*8 + (L>>3), c = (L&7)^(L>>3), dest chunk = wave*128+p*64+L.
__global__ __launch_bounds__(256, 4)
void fa_fwd(const short* __restrict__ Qc, const short* __restrict__ Kc,
            const short* __restrict__ Vt, float* __restrict__ Og)
{
    __shared__ short sA[8192];   // [0:4096)=K tile swz, [4096:8192)=V^T tile swz
    __shared__ short sB[8192];
    __shared__ float sL[4][64];

    const int tid  = threadIdx.x;
    const int wave = tid >> 6;
    const int lane = tid & 63;
    const int m    = lane & 15;
    const int quad = lane >> 4;
    const int h = blockIdx.y, b = blockIdx.z;
    const int qbase = blockIdx.x * 64;
    const int bh = b * HNUM + h;

    const short* Kbh = Kc + (size_t)bh * SLEN * EDIM;
    const short* Vbh = Vt + (size_t)bh * EDIM * SLEN;

    // staging coords
    const int rr = wave * 16 + (lane >> 3);
    const int cc = (lane & 7) ^ (lane >> 3);
    const int offK0 = (wave * 128 + lane) * 8;
    const int offK1 = offK0 + 512;
    const int offV0 = 4096 + offK0;
    const int offV1 = 4096 + offK1;

#define STAGE_TILE(buf, s0)                                                   \
    do {                                                                      \
        stage16(Kbh + (size_t)((s0) + rr) * EDIM + cc * 8,      &buf[offK0]); \
        stage16(Kbh + (size_t)((s0) + rr + 8) * EDIM + cc * 8,  &buf[offK1]); \
        stage16(Vbh + (size_t)rr * SLEN + (s0) + cc * 8,        &buf[offV0]); \
        stage16(Vbh + (size_t)(rr + 8) * SLEN + (s0) + cc * 8,  &buf[offV1]); \
    } while (0)

    // Q fragments for all 4 q-tiles (B-operand: B[k=e=quad*8+j][n=q=m])
    bf16x8 qfrag[4][2];
    #pragma unroll
    for (int qt = 0; qt < 4; ++qt)
        #pragma unroll
        for (int kb = 0; kb < 2; ++kb)
            qfrag[qt][kb] = *(const bf16x8*)(Qc +
                (((size_t)(b * LLEN + qbase + qt * 16 + m) * HNUM + h) * EDIM + kb * 32 + quad * 8));

    // ds_read offsets (shorts)
    const int kOff0 = (wave * 16 + m) * 64 + ((quad) ^ (m & 7)) * 8;
    const int kOff1 = (wave * 16 + m) * 64 + ((4 + quad) ^ (m & 7)) * 8;
    const int vOff  = m * 64 + ((2 * wave + (quad >> 1)) ^ (m & 7)) * 8 + (quad & 1) * 4;

    f32x4 oacc[4][4];
    #pragma unroll
    for (int i = 0; i < 4; ++i)
        #pragma unroll
        for (int j = 0; j < 4; ++j) oacc[i][j] = (f32x4){0.f, 0.f, 0.f, 0.f};
    float lsum[4] = {0.f, 0.f, 0.f, 0.f};

#define COMPUTE_TILE(buf)                                                     \
    do {                                                                      \
        const short* sK_ = buf;                                               \
        const short* sV_ = buf + 4096;                                        \
        bf16x8 kf0 = *(const bf16x8*)(sK_ + kOff0);                           \
        bf16x8 kf1 = *(const bf16x8*)(sK_ + kOff1);                           \
        bf16x4 vf[4];                                                         \
        _Pragma("unroll")                                                     \
        for (int dt = 0; dt < 4; ++dt)                                        \
            vf[dt] = *(const bf16x4*)(sV_ + dt * 1024 + vOff);                \
        _Pragma("unroll")                                                     \
        for (int qt = 0; qt < 4; ++qt) {                                      \
            f32x4 acc = {0.f, 0.f, 0.f, 0.f};                                 \
            acc = __builtin_amdgcn_mfma_f32_16x16x32_bf16(kf0, qfrag[qt][0], acc, 0, 0, 0); \
            acc = __builtin_amdgcn_mfma_f32_16x16x32_bf16(kf1, qfrag[qt][1], acc, 0, 0, 0); \
            float p0 = __builtin_amdgcn_exp2f(acc[0]);                        \
            float p1 = __builtin_amdgcn_exp2f(acc[1]);                        \
            float p2 = __builtin_amdgcn_exp2f(acc[2]);                        \
            float p3 = __builtin_amdgcn_exp2f(acc[3]);                        \
            lsum[qt] += (p0 + p1) + (p2 + p3);                                \
            bf16x4 pf;                                                        \
            pf[0] = f2bf(p0); pf[1] = f2bf(p1); pf[2] = f2bf(p2); pf[3] = f2bf(p3); \
            _Pragma("unroll")                                                 \
            for (int dt = 0; dt < 4; ++dt)                                    \
                oacc[qt][dt] = __builtin_amdgcn_mfma_f32_16x16x16bf16_1k(pf, vf[dt], oacc[qt][dt], 0, 0, 0); \
        }                                                                     \
    } while (0)

    // ---- pipeline: stage(next) -> compute(cur) -> barrier (1 barrier/tile) ----
    STAGE_TILE(sA, 0);
    __syncthreads();
    for (int s0 = 0; s0 < SLEN; s0 += 128) {
        STAGE_TILE(sB, s0 + 64);
        COMPUTE_TILE(sA);
        __syncthreads();
        if (s0 + 128 < SLEN) STAGE_TILE(sA, s0 + 128);
        COMPUTE_TILE(sB);
        __syncthreads();
    }

    // ---- epilogue: reduce l and O across the 4 s-chunk waves ----
    #pragma unroll
    for (int qt = 0; qt < 4; ++qt) {
        float l = lsum[qt];
        l += __shfl_xor(l, 16);
        l += __shfl_xor(l, 32);
        if (lane < 16) sL[wave][qt * 16 + lane] = l;
    }
    __syncthreads();

    float* sO = (float*)sA;   // 4096 floats, [q][d]
    for (int w = 0; w < 4; ++w) {
        if (wave == w) {
            #pragma unroll
            for (int qt = 0; qt < 4; ++qt)
                #pragma unroll
                for (int dt = 0; dt < 4; ++dt)
                    #pragma unroll
                    for (int r = 0; r < 4; ++r) {
                        const int q = qt * 16 + quad * 4 + r;
                        const int d = dt * 16 + m;
                        if (w == 0) sO[q * 64 + d] = oacc[qt][dt][r];
                        else        sO[q * 64 + d] += oacc[qt][dt][r];
                    }
        }
        __syncthreads();
    }

    {
        const int q = tid >> 2;
        const int dcol = (tid & 3) * 16;
        const float l = sL[0][q] + sL[1][q] + sL[2][q] + sL[3][q];
        const float inv = 1.0f / l;
        float* orow = Og + ((size_t)(b * LLEN + qbase + q) * HNUM + h) * EDIM + dcol;
        #pragma unroll
        for (int j = 0; j < 4; ++j) {
            float4 v = *(const float4*)(sO + q * 64 + dcol + j * 4);
            v.x *= inv; v.y *= inv; v.z *= inv; v.w *= inv;
            *(float4*)(orow + j * 4) = v;
        }
    }
}

extern "C" void kernel_launch(void* const* d_in, const int* in_sizes, int n_in,
                              void* d_out, int out_size, void* d_ws, size_t ws_size,
                              hipStream_t stream) {
    const float* Q = (const float*)d_in[0];
    const float* K = (const float*)d_in[1];
    const float* V = (const float*)d_in[2];
    float* O = (float*)d_out;

    const size_t NE = (size_t)BNUM * LLEN * HNUM * EDIM;
    short* Qc = (short*)d_ws;
    short* Kc = Qc + NE;
    short* Vt = Kc + NE;

    prep<<<dim3(2048, 3), dim3(256), 0, stream>>>(Q, K, V, Qc, Kc, Vt);
    fa_fwd<<<dim3(LLEN / 64, HNUM, BNUM), dim3(256), 0, stream>>>(Qc, Kc, Vt, O);
}

// Round 5
// 187.773 us; speedup vs baseline: 1.9087x; 1.9087x over previous
//
#include <hip/hip_runtime.h>
#include <hip/hip_bf16.h>

// FullAttention fwd, B=4 L=S=2048 H=8 E=D=64, fp32 in/out.
// Round 5: R3 structure (single 16KB K+V LDS tile, prescaled-Q static-max
// softmax, S^T=K*Q^T via mfma 16x16x32, P-from-registers PV via
// mfma 16x16x16bf16_1k, cross-wave O reduce) with the iteration reordered for
// DMA/compute overlap at zero register cost:
//   ds_read cur frags -> barrier1 -> DMA(next tile, same buffer) -> compute
//   -> barrier2 (vmcnt drain lands AFTER compute)
// Safe because all waves hold the cur tile in registers before barrier1.
// R4's double-buffer variant spilled (555MB scratch writes); this doesn't.

#define BNUM 4
#define LLEN 2048
#define SLEN 2048
#define HNUM 8
#define EDIM 64

typedef __attribute__((ext_vector_type(8))) short bf16x8;
typedef __attribute__((ext_vector_type(4))) short bf16x4;
typedef __attribute__((ext_vector_type(4))) float f32x4;

__device__ __forceinline__ short f2bf(float f) {
    union { __hip_bfloat16 b; short s; } u;
    u.b = __float2bfloat16(f);
    return u.s;
}

#if __has_builtin(__builtin_amdgcn_global_load_lds)
#define HAVE_GLL 1
#else
#define HAVE_GLL 0
#endif

__device__ __forceinline__ void stage16(const short* g, short* l) {
#if HAVE_GLL
    __builtin_amdgcn_global_load_lds(
        (const __attribute__((address_space(1))) void*)g,
        (__attribute__((address_space(3))) void*)l, 16, 0, 0);
#else
    *(bf16x8*)l = *(const bf16x8*)g;
#endif
}

// ---- pre-pass (single launch): role = blockIdx.y ----
__global__ __launch_bounds__(256)
void prep(const float* __restrict__ Qg, const float* __restrict__ Kg,
          const float* __restrict__ Vg,
          short* __restrict__ Qc, short* __restrict__ Kc, short* __restrict__ Vt)
{
    __shared__ short tile[EDIM][80];
    const int role = blockIdx.y;
    if (role == 0) {
        const size_t t = (size_t)blockIdx.x * 256 + threadIdx.x;
        const float c = 0.18033688011112042f;   // (1/sqrt(64)) * log2(e)
        const float4* src = (const float4*)Qg + t * 2;
        float4 a = src[0], bb = src[1];
        bf16x8 o;
        o[0]=f2bf(a.x*c);  o[1]=f2bf(a.y*c);  o[2]=f2bf(a.z*c);  o[3]=f2bf(a.w*c);
        o[4]=f2bf(bb.x*c); o[5]=f2bf(bb.y*c); o[6]=f2bf(bb.z*c); o[7]=f2bf(bb.w*c);
        *((bf16x8*)Qc + t) = o;
    } else if (role == 1) {
        const int t = blockIdx.x * 256 + threadIdx.x;
        const int e8 = t & 7;
        const int tmp = t >> 3;
        const int h = tmp & 7;
        const int tmp2 = tmp >> 3;
        const int s = tmp2 & (SLEN - 1);
        const int b = tmp2 >> 11;
        const float4* src = (const float4*)(Kg + (((size_t)(b * SLEN + s) * HNUM + h) * EDIM + e8 * 8));
        float4 a = src[0], bb = src[1];
        bf16x8 o;
        o[0]=f2bf(a.x);  o[1]=f2bf(a.y);  o[2]=f2bf(a.z);  o[3]=f2bf(a.w);
        o[4]=f2bf(bb.x); o[5]=f2bf(bb.y); o[6]=f2bf(bb.z); o[7]=f2bf(bb.w);
        *(bf16x8*)(Kc + ((size_t)((b * HNUM + h) * SLEN + s) * EDIM + e8 * 8)) = o;
    } else {
        if (blockIdx.x >= 1024) return;
        const int x = blockIdx.x;
        const int s0 = (x & 31) * 64;
        const int bh = x >> 5;
        const int b = bh >> 3, h = bh & 7;
        {
            const int sr = threadIdx.x >> 2, dc = (threadIdx.x & 3) * 16;
            const float4* src = (const float4*)(Vg + (((size_t)(b * SLEN + s0 + sr) * HNUM + h) * EDIM + dc));
            #pragma unroll
            for (int j4 = 0; j4 < 4; ++j4) {
                float4 a = src[j4];
                tile[dc + j4*4 + 0][sr] = f2bf(a.x);
                tile[dc + j4*4 + 1][sr] = f2bf(a.y);
                tile[dc + j4*4 + 2][sr] = f2bf(a.z);
                tile[dc + j4*4 + 3][sr] = f2bf(a.w);
            }
        }
        __syncthreads();
        {
            const int dr = threadIdx.x >> 2, sc = (threadIdx.x & 3) * 16;
            short* dst = Vt + ((size_t)((b * HNUM + h) * EDIM + dr) * SLEN + s0 + sc);
            *(bf16x8*)dst       = *(const bf16x8*)&tile[dr][sc];
            *(bf16x8*)(dst + 8) = *(const bf16x8*)&tile[dr][sc + 8];
        }
    }
}

// ---- main kernel ----
// LDS tile layout (K and V^T halves): 64 rows x 8 chunks of 16B; chunk (r,c)
// stored at linear chunk r*8 + (c ^ (r&7)). Staging lane L (inst p) covers
// r = wave*16 + p*8 + (L>>3), c = (L&7)^(L>>3), dest chunk = wave*128+p*64+L.
__global__ __launch_bounds__(256, 4)
void fa_fwd(const short* __restrict__ Qc, const short* __restrict__ Kc,
            const short* __restrict__ Vt, float* __restrict__ Og)
{
    __shared__ short sKV[2][64 * 64];   // [0]=K [s][e] swz, [1]=V^T [d][s] swz
    __shared__ float sL[4][64];

    const int tid  = threadIdx.x;
    const int wave = tid >> 6;
    const int lane = tid & 63;
    const int m    = lane & 15;
    const int quad = lane >> 4;
    const int h = blockIdx.y, b = blockIdx.z;
    const int qbase = blockIdx.x * 64;
    const int bh = b * HNUM + h;

    const short* Kbh = Kc + (size_t)bh * SLEN * EDIM;
    const short* Vbh = Vt + (size_t)bh * EDIM * SLEN;

    // staging coords
    const int rr = wave * 16 + (lane >> 3);
    const int cc = (lane & 7) ^ (lane >> 3);
    short* ldsK0 = &sKV[0][0] + (wave * 128 + lane) * 8;
    short* ldsK1 = &sKV[0][0] + (wave * 128 + 64 + lane) * 8;
    short* ldsV0 = &sKV[1][0] + (wave * 128 + lane) * 8;
    short* ldsV1 = &sKV[1][0] + (wave * 128 + 64 + lane) * 8;

#define STAGE_TILE(s0)                                                        \
    do {                                                                      \
        stage16(Kbh + (size_t)((s0) + rr) * EDIM + cc * 8,      ldsK0);       \
        stage16(Kbh + (size_t)((s0) + rr + 8) * EDIM + cc * 8,  ldsK1);       \
        stage16(Vbh + (size_t)rr * SLEN + (s0) + cc * 8,        ldsV0);       \
        stage16(Vbh + (size_t)(rr + 8) * SLEN + (s0) + cc * 8,  ldsV1);       \
    } while (0)

    // Q fragments for all 4 q-tiles (B-operand: B[k=e=quad*8+j][n=q=m])
    bf16x8 qfrag[4][2];
    #pragma unroll
    for (int qt = 0; qt < 4; ++qt)
        #pragma unroll
        for (int kb = 0; kb < 2; ++kb)
            qfrag[qt][kb] = *(const bf16x8*)(Qc +
                (((size_t)(b * LLEN + qbase + qt * 16 + m) * HNUM + h) * EDIM + kb * 32 + quad * 8));

    // ds_read offsets (shorts)
    const int kOff0 = (wave * 16 + m) * 64 + ((quad) ^ (m & 7)) * 8;
    const int kOff1 = (wave * 16 + m) * 64 + ((4 + quad) ^ (m & 7)) * 8;
    const int vOff  = m * 64 + ((2 * wave + (quad >> 1)) ^ (m & 7)) * 8 + (quad & 1) * 4;

    f32x4 oacc[4][4];
    #pragma unroll
    for (int i = 0; i < 4; ++i)
        #pragma unroll
        for (int j = 0; j < 4; ++j) oacc[i][j] = (f32x4){0.f, 0.f, 0.f, 0.f};
    float lsum[4] = {0.f, 0.f, 0.f, 0.f};

    const short* sK = &sKV[0][0];
    const short* sV = &sKV[1][0];

    STAGE_TILE(0);
    __syncthreads();   // tile 0 resident

    for (int s0 = 0; s0 < SLEN; s0 += 64) {
        // ---- LDS -> registers: everything this wave needs from the tile ----
        bf16x8 kf0 = *(const bf16x8*)(sK + kOff0);
        bf16x8 kf1 = *(const bf16x8*)(sK + kOff1);
        bf16x4 vf[4];
        #pragma unroll
        for (int dt = 0; dt < 4; ++dt)
            vf[dt] = *(const bf16x4*)(sV + dt * 1024 + vOff);

        __syncthreads();   // barrier1: all waves hold tile in regs (vmcnt already 0)

        // ---- DMA next tile into the same buffer; overlaps compute below ----
        if (s0 + 64 < SLEN) STAGE_TILE(s0 + 64);

        // ---- compute on registers ----
        #pragma unroll
        for (int qt = 0; qt < 4; ++qt) {
            f32x4 acc = {0.f, 0.f, 0.f, 0.f};
            acc = __builtin_amdgcn_mfma_f32_16x16x32_bf16(kf0, qfrag[qt][0], acc, 0, 0, 0);
            acc = __builtin_amdgcn_mfma_f32_16x16x32_bf16(kf1, qfrag[qt][1], acc, 0, 0, 0);
            // p = exp2(score); static max (Q prescaled). C layout: s=quad*4+r, q=m.
            float p0 = __builtin_amdgcn_exp2f(acc[0]);
            float p1 = __builtin_amdgcn_exp2f(acc[1]);
            float p2 = __builtin_amdgcn_exp2f(acc[2]);
            float p3 = __builtin_amdgcn_exp2f(acc[3]);
            lsum[qt] += (p0 + p1) + (p2 + p3);
            bf16x4 pf;
            pf[0] = f2bf(p0); pf[1] = f2bf(p1); pf[2] = f2bf(p2); pf[3] = f2bf(p3);
            #pragma unroll
            for (int dt = 0; dt < 4; ++dt)
                oacc[qt][dt] = __builtin_amdgcn_mfma_f32_16x16x16bf16_1k(pf, vf[dt], oacc[qt][dt], 0, 0, 0);
        }

        __syncthreads();   // barrier2: vmcnt drain AFTER compute; next tile ready
    }

    // ---- epilogue: reduce l and O across the 4 s-chunk waves ----
    #pragma unroll
    for (int qt = 0; qt < 4; ++qt) {
        float l = lsum[qt];
        l += __shfl_xor(l, 16);
        l += __shfl_xor(l, 32);
        if (lane < 16) sL[wave][qt * 16 + lane] = l;
    }
    __syncthreads();

    float* sO = (float*)&sKV[0][0];   // 4096 floats, [q][d]
    for (int w = 0; w < 4; ++w) {
        if (wave == w) {
            #pragma unroll
            for (int qt = 0; qt < 4; ++qt)
                #pragma unroll
                for (int dt = 0; dt < 4; ++dt)
                    #pragma unroll
                    for (int r = 0; r < 4; ++r) {
                        const int q = qt * 16 + quad * 4 + r;
                        const int d = dt * 16 + m;
                        if (w == 0) sO[q * 64 + d] = oacc[qt][dt][r];
                        else        sO[q * 64 + d] += oacc[qt][dt][r];
                    }
        }
        __syncthreads();
    }

    {
        const int q = tid >> 2;
        const int dcol = (tid & 3) * 16;
        const float l = sL[0][q] + sL[1][q] + sL[2][q] + sL[3][q];
        const float inv = 1.0f / l;
        float* orow = Og + ((size_t)(b * LLEN + qbase + q) * HNUM + h) * EDIM + dcol;
        #pragma unroll
        for (int j = 0; j < 4; ++j) {
            float4 v = *(const float4*)(sO + q * 64 + dcol + j * 4);
            v.x *= inv; v.y *= inv; v.z *= inv; v.w *= inv;
            *(float4*)(orow + j * 4) = v;
        }
    }
}

extern "C" void kernel_launch(void* const* d_in, const int* in_sizes, int n_in,
                              void* d_out, int out_size, void* d_ws, size_t ws_size,
                              hipStream_t stream) {
    const float* Q = (const float*)d_in[0];
    const float* K = (const float*)d_in[1];
    const float* V = (const float*)d_in[2];
    float* O = (float*)d_out;

    const size_t NE = (size_t)BNUM * LLEN * HNUM * EDIM;
    short* Qc = (short*)d_ws;
    short* Kc = Qc + NE;
    short* Vt = Kc + NE;

    prep<<<dim3(2048, 3), dim3(256), 0, stream>>>(Q, K, V, Qc, Kc, Vt);
    fa_fwd<<<dim3(LLEN / 64, HNUM, BNUM), dim3(256), 0, stream>>>(Qc, Kc, Vt, O);
}

// Round 6
// 152.968 us; speedup vs baseline: 2.3430x; 1.2275x over previous
//
#include <hip/hip_runtime.h>
#include <hip/hip_bf16.h>

// FullAttention fwd, B=4 L=S=2048 H=8 E=D=64, fp32 in/out.
// Round 6: 128-wide s-tiles, wave owns a 32-s chunk. Permuted-K QK trick:
// A-rows of QK fed as pi0(m)=8*(m>>2)+(m&3), pi1=pi0+4, so the two QK C-layouts
// give lane `quad` P for s_local=quad*8+{0..7} == A-layout of 16x16x32 MFMA ->
// PV runs at FULL rate (16 K=32 MFMAs) with zero LDS round-trip for P.
// K/V staged by global_load_lds(16B) with XOR swizzles; all LDS frag reads are
// balanced b128 (conflict-free). Q conversion (prescale by 0.125*log2e) folded
// into the main kernel. launch_bounds(256,3): R5 was at the 128-reg cap; this
// needs ~150 unified regs -> cap 170 avoids R4-style spill.

#define BNUM 4
#define LLEN 2048
#define SLEN 2048
#define HNUM 8
#define EDIM 64

typedef __attribute__((ext_vector_type(8))) short bf16x8;
typedef __attribute__((ext_vector_type(4))) float f32x4;

__device__ __forceinline__ short f2bf(float f) {
    union { __hip_bfloat16 b; short s; } u;
    u.b = __float2bfloat16(f);
    return u.s;
}

#if __has_builtin(__builtin_amdgcn_global_load_lds)
#define HAVE_GLL 1
#else
#define HAVE_GLL 0
#endif

__device__ __forceinline__ void stage16(const short* g, short* l) {
#if HAVE_GLL
    __builtin_amdgcn_global_load_lds(
        (const __attribute__((address_space(1))) void*)g,
        (__attribute__((address_space(3))) void*)l, 16, 0, 0);
#else
    *(bf16x8*)l = *(const bf16x8*)g;
#endif
}

// ---- pre-pass: role 0 = K repack, role 1 = V transpose (Q handled in main) ----
__global__ __launch_bounds__(256)
void prep(const float* __restrict__ Kg, const float* __restrict__ Vg,
          short* __restrict__ Kc, short* __restrict__ Vt)
{
    __shared__ short tile[EDIM][80];
    if (blockIdx.y == 0) {
        // K [b][s][h][e] fp32 -> Kc [b][h][s][e] bf16
        const int t = blockIdx.x * 256 + threadIdx.x;
        const int e8 = t & 7;
        const int tmp = t >> 3;
        const int h = tmp & 7;
        const int tmp2 = tmp >> 3;
        const int s = tmp2 & (SLEN - 1);
        const int b = tmp2 >> 11;
        const float4* src = (const float4*)(Kg + (((size_t)(b * SLEN + s) * HNUM + h) * EDIM + e8 * 8));
        float4 a = src[0], bb = src[1];
        bf16x8 o;
        o[0]=f2bf(a.x);  o[1]=f2bf(a.y);  o[2]=f2bf(a.z);  o[3]=f2bf(a.w);
        o[4]=f2bf(bb.x); o[5]=f2bf(bb.y); o[6]=f2bf(bb.z); o[7]=f2bf(bb.w);
        *(bf16x8*)(Kc + ((size_t)((b * HNUM + h) * SLEN + s) * EDIM + e8 * 8)) = o;
    } else {
        // V [b][s][h][d] fp32 -> Vt [b][h][d][s] bf16 (64x64 tile transpose)
        if (blockIdx.x >= 1024) return;
        const int x = blockIdx.x;
        const int s0 = (x & 31) * 64;
        const int bh = x >> 5;
        const int b = bh >> 3, h = bh & 7;
        {
            const int sr = threadIdx.x >> 2, dc = (threadIdx.x & 3) * 16;
            const float4* src = (const float4*)(Vg + (((size_t)(b * SLEN + s0 + sr) * HNUM + h) * EDIM + dc));
            #pragma unroll
            for (int j4 = 0; j4 < 4; ++j4) {
                float4 a = src[j4];
                tile[dc + j4*4 + 0][sr] = f2bf(a.x);
                tile[dc + j4*4 + 1][sr] = f2bf(a.y);
                tile[dc + j4*4 + 2][sr] = f2bf(a.z);
                tile[dc + j4*4 + 3][sr] = f2bf(a.w);
            }
        }
        __syncthreads();
        {
            const int dr = threadIdx.x >> 2, sc = (threadIdx.x & 3) * 16;
            short* dst = Vt + ((size_t)((b * HNUM + h) * EDIM + dr) * SLEN + s0 + sc);
            *(bf16x8*)dst       = *(const bf16x8*)&tile[dr][sc];
            *(bf16x8*)(dst + 8) = *(const bf16x8*)&tile[dr][sc + 8];
        }
    }
}

// ---- main kernel ----
// LDS: K region 128 rows x 8 chunks(16B), chunk (r,c) at r*8 + (c ^ g(r)),
//      g(r) = ((r>>3)&1)*4 + (r&3).
//      V region (offset 8192 shorts): 4 panels (s-window per wave), panel =
//      64 d-rows x 4 chunks(16B), chunk (d,c) at d*4 + (c ^ (d&3)).
__global__ __launch_bounds__(256, 3)
void fa_fwd(const float* __restrict__ Qg, const short* __restrict__ Kc,
            const short* __restrict__ Vt, float* __restrict__ Og)
{
    __shared__ short sKV[16384];   // 32 KB: [0:8192)=K, [8192:16384)=V^T panels
    __shared__ float sL[4][64];

    const int tid  = threadIdx.x;
    const int wave = tid >> 6;
    const int lane = tid & 63;
    const int m    = lane & 15;
    const int quad = lane >> 4;
    const int h = blockIdx.y, b = blockIdx.z;
    const int qbase = blockIdx.x * 64;
    const int bh = b * HNUM + h;

    const short* Kbh = Kc + (size_t)bh * SLEN * EDIM;
    const short* Vbh = Vt + (size_t)bh * EDIM * SLEN;

    // ---- staging address precompute (element offsets, minus the s0 term) ----
    int ksrc[4], vsrc[4];
    short *kdst[4], *vdst[4];
    #pragma unroll
    for (int p = 0; p < 4; ++p) {
        const int krow = wave * 32 + p * 8 + (lane >> 3);
        const int kchk = (lane & 7) ^ ((p & 1) * 4 + ((lane >> 3) & 3));
        ksrc[p] = krow * EDIM + kchk * 8;                 // + s0*EDIM per iter
        kdst[p] = sKV + (wave * 256 + p * 64 + lane) * 8;
        const int vrow = p * 16 + (lane >> 2);
        const int vchk = (lane & 3) ^ ((lane >> 2) & 3);
        vsrc[p] = vrow * SLEN + wave * 32 + vchk * 8;     // + s0 per iter
        vdst[p] = sKV + 8192 + (wave * 256 + p * 64 + lane) * 8;
    }

#define STAGE_TILE(s0)                                                  \
    do {                                                                \
        _Pragma("unroll")                                               \
        for (int p = 0; p < 4; ++p) {                                   \
            stage16(Kbh + (size_t)(s0) * EDIM + ksrc[p], kdst[p]);      \
            stage16(Vbh + (s0) + vsrc[p], vdst[p]);                     \
        }                                                               \
    } while (0)

    // ---- Q fragments from global fp32, prescaled (B-op: B[k=e][n=q=m]) ----
    const float csc = 0.18033688011112042f;   // (1/sqrt(64)) * log2(e)
    bf16x8 qfrag[4][2];
    #pragma unroll
    for (int qt = 0; qt < 4; ++qt)
        #pragma unroll
        for (int kb = 0; kb < 2; ++kb) {
            const float* qp = Qg + ((size_t)(b * LLEN + qbase + qt * 16 + m) * HNUM + h) * EDIM
                              + kb * 32 + quad * 8;
            float4 x0 = *(const float4*)qp;
            float4 x1 = *(const float4*)(qp + 4);
            bf16x8 f;
            f[0]=f2bf(x0.x*csc); f[1]=f2bf(x0.y*csc); f[2]=f2bf(x0.z*csc); f[3]=f2bf(x0.w*csc);
            f[4]=f2bf(x1.x*csc); f[5]=f2bf(x1.y*csc); f[6]=f2bf(x1.z*csc); f[7]=f2bf(x1.w*csc);
            qfrag[qt][kb] = f;
        }

    // ---- frag read offsets (shorts) ----
    // K rows permuted: pi0 = 8*(m>>2)+(m&3), pi1 = pi0+4; g(row)=((m>>2)&1)*4+(m&3)
    const int gk  = ((m >> 2) & 1) * 4 + (m & 3);
    const int pi0 = 8 * (m >> 2) + (m & 3);
    const int kOff00 = (wave * 32 + pi0)     * EDIM + ((quad)     ^ gk) * 8;
    const int kOff01 = (wave * 32 + pi0)     * EDIM + ((4 + quad) ^ gk) * 8;
    const int kOff10 = (wave * 32 + pi0 + 4) * EDIM + ((quad)     ^ gk) * 8;
    const int kOff11 = (wave * 32 + pi0 + 4) * EDIM + ((4 + quad) ^ gk) * 8;
    // V: panel=wave, row d=dt*16+m, chunk quad (swz by d&3=m&3)
    const int vOffB = 8192 + wave * 2048 + m * 32 + ((quad ^ (m & 3)) * 8);

    f32x4 oacc[4][4];
    #pragma unroll
    for (int i = 0; i < 4; ++i)
        #pragma unroll
        for (int j = 0; j < 4; ++j) oacc[i][j] = (f32x4){0.f, 0.f, 0.f, 0.f};
    float lsum[4] = {0.f, 0.f, 0.f, 0.f};

    STAGE_TILE(0);
    __syncthreads();   // tile 0 resident

    for (int s0 = 0; s0 < SLEN; s0 += 128) {
        // ---- LDS -> registers (all balanced b128, conflict-free) ----
        bf16x8 kf00 = *(const bf16x8*)(sKV + kOff00);
        bf16x8 kf01 = *(const bf16x8*)(sKV + kOff01);
        bf16x8 kf10 = *(const bf16x8*)(sKV + kOff10);
        bf16x8 kf11 = *(const bf16x8*)(sKV + kOff11);
        bf16x8 vf[4];
        #pragma unroll
        for (int dt = 0; dt < 4; ++dt)
            vf[dt] = *(const bf16x8*)(sKV + vOffB + dt * 512);

        __syncthreads();   // barrier1: all waves hold tile in regs

        if (s0 + 128 < SLEN) STAGE_TILE(s0 + 128);   // DMA next; overlaps compute

        // ---- compute: 32 full-rate MFMAs per wave ----
        #pragma unroll
        for (int qt = 0; qt < 4; ++qt) {
            f32x4 a0 = {0.f, 0.f, 0.f, 0.f};
            f32x4 a1 = {0.f, 0.f, 0.f, 0.f};
            a0 = __builtin_amdgcn_mfma_f32_16x16x32_bf16(kf00, qfrag[qt][0], a0, 0, 0, 0);
            a0 = __builtin_amdgcn_mfma_f32_16x16x32_bf16(kf01, qfrag[qt][1], a0, 0, 0, 0);
            a1 = __builtin_amdgcn_mfma_f32_16x16x32_bf16(kf10, qfrag[qt][0], a1, 0, 0, 0);
            a1 = __builtin_amdgcn_mfma_f32_16x16x32_bf16(kf11, qfrag[qt][1], a1, 0, 0, 0);
            // a0[r] = S[s_local=8*quad+r][q], a1[r] = S[s_local=8*quad+4+r][q]
            float p0 = __builtin_amdgcn_exp2f(a0[0]);
            float p1 = __builtin_amdgcn_exp2f(a0[1]);
            float p2 = __builtin_amdgcn_exp2f(a0[2]);
            float p3 = __builtin_amdgcn_exp2f(a0[3]);
            float p4 = __builtin_amdgcn_exp2f(a1[0]);
            float p5 = __builtin_amdgcn_exp2f(a1[1]);
            float p6 = __builtin_amdgcn_exp2f(a1[2]);
            float p7 = __builtin_amdgcn_exp2f(a1[3]);
            lsum[qt] += ((p0 + p1) + (p2 + p3)) + ((p4 + p5) + (p6 + p7));
            bf16x8 pf;   // A-op of 16x16x32: A[q=m][k=s_local=quad*8+j]
            pf[0]=f2bf(p0); pf[1]=f2bf(p1); pf[2]=f2bf(p2); pf[3]=f2bf(p3);
            pf[4]=f2bf(p4); pf[5]=f2bf(p5); pf[6]=f2bf(p6); pf[7]=f2bf(p7);
            #pragma unroll
            for (int dt = 0; dt < 4; ++dt)
                oacc[qt][dt] = __builtin_amdgcn_mfma_f32_16x16x32_bf16(pf, vf[dt], oacc[qt][dt], 0, 0, 0);
        }

        __syncthreads();   // barrier2: DMA drained after compute; next tile ready
    }

    // ---- epilogue: reduce l and O across the 4 s-chunk waves ----
    #pragma unroll
    for (int qt = 0; qt < 4; ++qt) {
        float l = lsum[qt];
        l += __shfl_xor(l, 16);
        l += __shfl_xor(l, 32);
        if (lane < 16) sL[wave][qt * 16 + lane] = l;
    }
    __syncthreads();

    float* sO = (float*)sKV;   // 4096 floats = 16 KB, [q][d]
    for (int w = 0; w < 4; ++w) {
        if (wave == w) {
            #pragma unroll
            for (int qt = 0; qt < 4; ++qt)
                #pragma unroll
                for (int dt = 0; dt < 4; ++dt)
                    #pragma unroll
                    for (int r = 0; r < 4; ++r) {
                        const int q = qt * 16 + quad * 4 + r;
                        const int d = dt * 16 + m;
                        if (w == 0) sO[q * 64 + d] = oacc[qt][dt][r];
                        else        sO[q * 64 + d] += oacc[qt][dt][r];
                    }
        }
        __syncthreads();
    }

    {
        const int q = tid >> 2;
        const int dcol = (tid & 3) * 16;
        const float l = sL[0][q] + sL[1][q] + sL[2][q] + sL[3][q];
        const float inv = 1.0f / l;
        float* orow = Og + ((size_t)(b * LLEN + qbase + q) * HNUM + h) * EDIM + dcol;
        #pragma unroll
        for (int j = 0; j < 4; ++j) {
            float4 v = *(const float4*)(sO + q * 64 + dcol + j * 4);
            v.x *= inv; v.y *= inv; v.z *= inv; v.w *= inv;
            *(float4*)(orow + j * 4) = v;
        }
    }
}

extern "C" void kernel_launch(void* const* d_in, const int* in_sizes, int n_in,
                              void* d_out, int out_size, void* d_ws, size_t ws_size,
                              hipStream_t stream) {
    const float* Q = (const float*)d_in[0];
    const float* K = (const float*)d_in[1];
    const float* V = (const float*)d_in[2];
    float* O = (float*)d_out;

    const size_t NE = (size_t)BNUM * LLEN * HNUM * EDIM;   // 4,194,304
    short* Kc = (short*)d_ws;
    short* Vt = Kc + NE;

    prep<<<dim3(2048, 2), dim3(256), 0, stream>>>(K, V, Kc, Vt);
    fa_fwd<<<dim3(LLEN / 64, HNUM, BNUM), dim3(256), 0, stream>>>(Q, Kc, Vt, O);
}